// Round 5
// baseline (1521.718 us; speedup 1.0000x reference)
//
#include <hip/hip_runtime.h>
#include <hip/hip_bf16.h>
#include <math.h>

typedef __bf16 bf16_t;
typedef __attribute__((ext_vector_type(8))) __bf16 bf16x8;
typedef __attribute__((ext_vector_type(4))) __bf16 bf16x4;
typedef __attribute__((ext_vector_type(16))) float f32x16;

#define DEVI __device__ __forceinline__

constexpr int B_SZ = 16384, DIN = 2048, DK = 2048, DV = 2048, NH = 16, DOUT = 512;

DEVI void load_lds16(const void* gptr, void* lptr) {
  __builtin_amdgcn_global_load_lds(
      (const __attribute__((address_space(1))) unsigned int*)gptr,
      (__attribute__((address_space(3))) unsigned int*)lptr,
      16, 0, 0);
}

// ---------------------------------------------------------------------------
// 256x256 phased bf16 GEMM (B transposed), BK=64, 512 thr = 8 waves (2M x 4N).
// Each wave owns 128x64 via acc[4][2] of 32x32x16 MFMA.
// LDS 128 KiB: 2 buffers x (A 256x64 | B 256x64), rows 128 B.
// Swizzle v2 (r3: conflicts -> 0): 16B-slot ^= f(row), f(r)=(r&7)^((r>>3)&3).
// global_load_lds writes linearly -> swizzle pre-applied on the GLOBAL source.
//
// r4 schedule: 2 barriers per K-tile, both AFTER the MFMA cluster. The
// pre-MFMA barriers were correctness-redundant (phase MFMA consumes only
// own-wave ds_reads of buf[cur], valid since the previous end-of-tile
// vmcnt+barrier) and serialized the LDS-read burst against the MFMA burst
// across all 8 waves (r3: MfmaUtil 48% with LDS traffic ~= MFMA time).
// Removing them lets waves skew inside each half-tile so LDS reads of one
// wave hide under MFMA of another; setprio(1) arbitrates for the MFMA wave.
// Hazard ledger (unchanged invariants):
//  - mid-tile lgkm(0)+barrier: all waves' bq reads (phA) done before any
//    stageB (t+2) can clobber buf[cur].B.
//  - end-of-tile vmcnt(4)+barrier: retires (t+1).A (issued phA this tile)
//    and (t+1).B (issued phB last tile, older) => buf^1 fully staged before
//    next tile reads it; (t+2).B's 4 loads stay in flight. Never vmcnt(0)
//    in steady state.
//  - stageA (t+1, buf^1.A) issued after end-of-tile barrier of t-1, which
//    followed all af reads of buf^1.A at t-1.
// ---------------------------------------------------------------------------
template <int EPI>
__global__ __launch_bounds__(512, 2) void gemm256(
    const bf16_t* __restrict__ A, int lda, long aZ,
    const bf16_t* __restrict__ Bt, int ldb, long bZ,
    void* __restrict__ Cv, int ldc, long cZ, int K,
    const float* __restrict__ aux1,   // bias
    const float* __restrict__ aux2) { // x (EPI4)
  __shared__ __align__(16) bf16_t lds[2][2][256 * 64];
  const int tid = threadIdx.x;
  // XCD-bijective swizzle (all launch grids have nwg % 8 == 0)
  const int gx = gridDim.x;
  const int nwg = gx * gridDim.y;
  int flat = blockIdx.y * gx + blockIdx.x;
  flat = (flat & 7) * (nwg >> 3) + (flat >> 3);
  const int bn = flat % gx, bm = flat / gx;
  const int bz = blockIdx.z;

  const int lane = tid & 63, w = tid >> 6;
  const int wr = w >> 2, wc = w & 3;      // wave 2x4 -> (128-row, 64-col) tile
  const int lm = lane & 31, lh = lane >> 5;

  const bf16_t* __restrict__ Ab = A + (long)bm * 256 * lda + (long)bz * aZ;
  const bf16_t* __restrict__ Bb = Bt + (long)bn * 256 * ldb + (long)bz * bZ;

  // staging: granule g = tid within an 8KB (64-row) chunk; pre-swizzled source.
  const int srow = tid >> 3;                       // 0..63
  const int fs = (srow & 7) ^ ((srow >> 3) & 3);
  const int sslot = (tid & 7) ^ fs;                // inverse swizzle on source
  const long aOff = (long)srow * lda + sslot * 8;
  const long bOff = (long)srow * ldb + sslot * 8;
  char* const ldsc = (char*)&lds[0][0][0];         // buf stride 65536, mat 32768

  // fragment read addressing (swizzled). All read-row bases are multiples of
  // 32, so f(row) = (lm&7) ^ ((lm>>3)&3) for every fragment read.
  const int xorv = (lm & 7) ^ ((lm >> 3) & 3);
  const int rbA = (wr * 128 + lm) * 128;           // row byte base, A
  const int rbB = (wc * 64 + lm) * 128 + 32768;    // row byte base, B
  int sl16[4];
#pragma unroll
  for (int s = 0; s < 4; ++s) sl16[s] = (((2 * s) | lh) ^ xorv) * 16;

  auto stageA = [&](int buf, int t, int h) {       // h: 128-row half; 2 loads
    const bf16_t* p = Ab + aOff + t * 64 + (long)h * 128 * lda;
    char* d = ldsc + buf * 65536 + h * 16384 + tid * 16;
    load_lds16(p, d);
    load_lds16(p + (long)64 * lda, d + 8192);
  };
  auto stageB = [&](int buf, int t, int h) {
    const bf16_t* p = Bb + bOff + t * 64 + (long)h * 128 * ldb;
    char* d = ldsc + buf * 65536 + 32768 + h * 16384 + tid * 16;
    load_lds16(p, d);
    load_lds16(p + (long)64 * ldb, d + 8192);
  };

  f32x16 acc[4][2] = {};
  const int NT = K >> 6;

  // prologue: tile0 full -> buf0; tile1 B -> buf1 (A of tile1 staged in iter0)
  stageA(0, 0, 0); stageA(0, 0, 1); stageB(0, 0, 0); stageB(0, 0, 1);
  if (NT > 1) {
    stageB(1, 1, 0); stageB(1, 1, 1);
    asm volatile("s_waitcnt vmcnt(4)" ::: "memory");  // tile0 landed, t1.B flying
  } else {
    asm volatile("s_waitcnt vmcnt(0)" ::: "memory");
  }
  __builtin_amdgcn_sched_barrier(0);
  __builtin_amdgcn_s_barrier();

  for (int t = 0; t < NT; ++t) {
    const int cur = t & 1;
    const char* base = ldsc + cur * 65536;
    bf16x8 af[2][4], bq[2][4];
    // ---- half A: reads (af0|bq|af1) + stageA(t+1) + MFMA m=0,1 ----
#pragma unroll
    for (int s = 0; s < 4; ++s)
      af[0][s] = *(const bf16x8*)(base + rbA + 0 * 4096 + sl16[s]);
#pragma unroll
    for (int j = 0; j < 2; ++j)
#pragma unroll
      for (int s = 0; s < 4; ++s)
        bq[j][s] = *(const bf16x8*)(base + rbB + j * 4096 + sl16[s]);
#pragma unroll
    for (int s = 0; s < 4; ++s)
      af[1][s] = *(const bf16x8*)(base + rbA + 1 * 4096 + sl16[s]);
    if (t + 1 < NT) { stageA(cur ^ 1, t + 1, 0); stageA(cur ^ 1, t + 1, 1); }
    __builtin_amdgcn_s_setprio(1);
#pragma unroll
    for (int s = 0; s < 4; ++s) {
      acc[0][0] = __builtin_amdgcn_mfma_f32_32x32x16_bf16(af[0][s], bq[0][s], acc[0][0], 0, 0, 0);
      acc[0][1] = __builtin_amdgcn_mfma_f32_32x32x16_bf16(af[0][s], bq[1][s], acc[0][1], 0, 0, 0);
      acc[1][0] = __builtin_amdgcn_mfma_f32_32x32x16_bf16(af[1][s], bq[0][s], acc[1][0], 0, 0, 0);
      acc[1][1] = __builtin_amdgcn_mfma_f32_32x32x16_bf16(af[1][s], bq[1][s], acc[1][1], 0, 0, 0);
    }
    __builtin_amdgcn_s_setprio(0);
    asm volatile("s_waitcnt lgkmcnt(0)" ::: "memory");
    __builtin_amdgcn_sched_barrier(0);
    __builtin_amdgcn_s_barrier();   // all waves' buf[cur].B reads complete
    // ---- half B: reads (af2|af3) + stageB(t+2) + MFMA m=2,3 ----
#pragma unroll
    for (int s = 0; s < 4; ++s)
      af[0][s] = *(const bf16x8*)(base + rbA + 2 * 4096 + sl16[s]);
#pragma unroll
    for (int s = 0; s < 4; ++s)
      af[1][s] = *(const bf16x8*)(base + rbA + 3 * 4096 + sl16[s]);
    if (t + 2 < NT) { stageB(cur, t + 2, 0); stageB(cur, t + 2, 1); }
    __builtin_amdgcn_s_setprio(1);
#pragma unroll
    for (int s = 0; s < 4; ++s) {
      acc[2][0] = __builtin_amdgcn_mfma_f32_32x32x16_bf16(af[0][s], bq[0][s], acc[2][0], 0, 0, 0);
      acc[2][1] = __builtin_amdgcn_mfma_f32_32x32x16_bf16(af[0][s], bq[1][s], acc[2][1], 0, 0, 0);
      acc[3][0] = __builtin_amdgcn_mfma_f32_32x32x16_bf16(af[1][s], bq[0][s], acc[3][0], 0, 0, 0);
      acc[3][1] = __builtin_amdgcn_mfma_f32_32x32x16_bf16(af[1][s], bq[1][s], acc[3][1], 0, 0, 0);
    }
    __builtin_amdgcn_s_setprio(0);
    if (t + 2 < NT) asm volatile("s_waitcnt vmcnt(4) lgkmcnt(0)" ::: "memory");
    else            asm volatile("s_waitcnt vmcnt(0) lgkmcnt(0)" ::: "memory");
    __builtin_amdgcn_sched_barrier(0);
    __builtin_amdgcn_s_barrier();   // buf^1 fully staged for next tile
  }

  // C/D: col = lane&31, row = (reg&3) + 8*(reg>>2) + 4*(lane>>5)
#pragma unroll
  for (int i = 0; i < 4; ++i) {
#pragma unroll
    for (int j = 0; j < 2; ++j) {
      const int col = bn * 256 + wc * 64 + j * 32 + lm;
#pragma unroll
      for (int r = 0; r < 16; ++r) {
        const int row = bm * 256 + wr * 128 + i * 32 + (r & 3) + 8 * (r >> 2) + 4 * lh;
        const long cidx = (long)row * ldc + (long)bz * cZ + col;
        float val = acc[i][j][r];
        if (EPI == 0) {
          ((bf16_t*)Cv)[cidx] = (bf16_t)val;
        } else if (EPI == 1) {
          if (col < 4096) val = fmaxf(val, 0.f) + 1e-4f;  // q,k feat; v plain
          ((bf16_t*)Cv)[cidx] = (bf16_t)val;
        } else if (EPI == 2) {
          val += aux1[col];
          ((bf16_t*)Cv)[cidx] = (bf16_t)val;
        } else if (EPI == 4) {
          const float g = 1.f / (1.f + __expf(-(val + aux1[col])));
          const float op = (float)A[(long)row * lda + col];  // concat cols [0,2048)
          const float xx = aux2[(long)row * DIN + col];
          ((bf16_t*)Cv)[cidx] = (bf16_t)(g * op + (1.f - g) * xx);
        } else if (EPI == 5) {
          ((float*)Cv)[cidx] = val + aux1[col];
        }
      }
    }
  }
}

// ---------------------------------------------------------------------------
// legacy 128x128 GEMM — kept for the small/odd shapes (G per-head, final N=512)
// ---------------------------------------------------------------------------
template <int EPI>
__global__ __launch_bounds__(256, 4) void gemm_bt(
    const bf16_t* __restrict__ A, int lda, long aZ,
    const bf16_t* __restrict__ Bt, int ldb, long bZ,
    void* __restrict__ Cv, int ldc, long cZ, int K,
    const float* __restrict__ aux1,
    const float* __restrict__ aux2) {
  __shared__ __align__(16) bf16_t As[2][128 * 32];
  __shared__ __align__(16) bf16_t Bs[2][128 * 32];
  const int tid = threadIdx.x;
  const int bn = blockIdx.x, bm = blockIdx.y, bz = blockIdx.z;
  const int lane = tid & 63, w = tid >> 6;
  const int wm = (w & 1) * 64, wn = (w >> 1) * 64;
  const int lm = lane & 31, lh = lane >> 5;

  const bf16_t* __restrict__ Ab = A + (long)bm * 128 * lda + (long)bz * aZ;
  const bf16_t* __restrict__ Bb = Bt + (long)bn * 128 * ldb + (long)bz * bZ;

  const int srow = tid >> 2, scol = (tid & 3) * 8;
  const long aRow = (long)srow * lda + scol;
  const long bRow = (long)srow * ldb + scol;

  const char* aBase = (const char*)As + (wm + lm) * 64 + lh * 16;
  const char* bBase = (const char*)Bs + (wn + lm) * 64 + lh * 16;

  f32x16 acc[2][2] = {};

  for (int k0 = 0; k0 < K; k0 += 64) {
    const bf16_t* ap = Ab + aRow + k0;
    const bf16_t* bp = Bb + bRow + k0;
    load_lds16(ap, &As[0][tid * 8]);
    load_lds16(ap + (long)64 * lda, &As[0][2048 + tid * 8]);
    load_lds16(ap + 32, &As[1][tid * 8]);
    load_lds16(ap + (long)64 * lda + 32, &As[1][2048 + tid * 8]);
    load_lds16(bp, &Bs[0][tid * 8]);
    load_lds16(bp + (long)64 * ldb, &Bs[0][2048 + tid * 8]);
    load_lds16(bp + 32, &Bs[1][tid * 8]);
    load_lds16(bp + (long)64 * ldb + 32, &Bs[1][2048 + tid * 8]);
    __syncthreads();
#pragma unroll
    for (int s = 0; s < 4; ++s) {
      const int off = (s >> 1) * 8192 + (s & 1) * 32;
      const bf16x8 af0 = *(const bf16x8*)(aBase + off);
      const bf16x8 af1 = *(const bf16x8*)(aBase + off + 2048);
      const bf16x8 bf0 = *(const bf16x8*)(bBase + off);
      const bf16x8 bf1 = *(const bf16x8*)(bBase + off + 2048);
      acc[0][0] = __builtin_amdgcn_mfma_f32_32x32x16_bf16(af0, bf0, acc[0][0], 0, 0, 0);
      acc[0][1] = __builtin_amdgcn_mfma_f32_32x32x16_bf16(af0, bf1, acc[0][1], 0, 0, 0);
      acc[1][0] = __builtin_amdgcn_mfma_f32_32x32x16_bf16(af1, bf0, acc[1][0], 0, 0, 0);
      acc[1][1] = __builtin_amdgcn_mfma_f32_32x32x16_bf16(af1, bf1, acc[1][1], 0, 0, 0);
    }
    __syncthreads();
  }

#pragma unroll
  for (int i = 0; i < 2; ++i) {
#pragma unroll
    for (int j = 0; j < 2; ++j) {
      const int col = bn * 128 + wn + j * 32 + lm;
#pragma unroll
      for (int r = 0; r < 16; ++r) {
        const int row = bm * 128 + wm + i * 32 + (r & 3) + 8 * (r >> 2) + 4 * lh;
        const long cidx = (long)row * ldc + (long)bz * cZ + col;
        float val = acc[i][j][r];
        if (EPI == 0) {
          ((bf16_t*)Cv)[cidx] = (bf16_t)val;
        } else if (EPI == 5) {
          ((float*)Cv)[cidx] = val + aux1[col];
        }
      }
    }
  }
}

// ---------------------------------------------------------------------------
// Fused prep: cvt_x (blocks [0, 32768)) + 6 weight transposes (f32 -> bf16^T)
// ---------------------------------------------------------------------------
__global__ __launch_bounds__(256) void prep_kernel(
    const float* __restrict__ x, const float* __restrict__ Wq,
    const float* __restrict__ Wk, const float* __restrict__ Wv,
    const float* __restrict__ Wo, const float* __restrict__ Wg,
    const float* __restrict__ Wout, bf16_t* __restrict__ concat,
    bf16_t* __restrict__ WqkvT, bf16_t* __restrict__ WoT,
    bf16_t* __restrict__ WgT, bf16_t* __restrict__ WoutT) {
  const int tid = threadIdx.x;
  int b = blockIdx.x;
  if (b < 32768) {  // cvt_x: x f32 -> bf16 into concat cols [2048,4096)
    const long i = ((long)b * 256 + tid) * 4;
    const long row = i >> 11;
    const int col = (int)(i & 2047);
    const float4 f = *(const float4*)&x[i];
    bf16x4 o;
    o[0] = (bf16_t)f.x; o[1] = (bf16_t)f.y; o[2] = (bf16_t)f.z; o[3] = (bf16_t)f.w;
    *(bf16x4*)&concat[row * 4096 + 2048 + col] = o;
    return;
  }
  b -= 32768;
  const float* in; bf16_t* out; int R, C;
  if (b < 4096)       { in = Wq;   out = WqkvT;                     R = 2048; C = 2048; }
  else if (b < 8192)  { in = Wk;   out = WqkvT + (size_t)2048*2048; R = 2048; C = 2048; b -= 4096; }
  else if (b < 12288) { in = Wv;   out = WqkvT + (size_t)4096*2048; R = 2048; C = 2048; b -= 8192; }
  else if (b < 16384) { in = Wo;   out = WoT;                       R = 2048; C = 2048; b -= 12288; }
  else if (b < 24576) { in = Wg;   out = WgT;                       R = 4096; C = 2048; b -= 16384; }
  else                { in = Wout; out = WoutT;                     R = 2048; C = 512;  b -= 24576; }
  const int CB = C / 32;
  const int c0 = (b % CB) * 32, r0 = (b / CB) * 32;
  __shared__ bf16_t tile[32][33];
  const int tx = tid & 31, ty = tid >> 5;
  for (int i = ty; i < 32; i += 8)
    tile[i][tx] = (bf16_t)in[(long)(r0 + i) * C + c0 + tx];
  __syncthreads();
  for (int i = ty; i < 32; i += 8)
    out[(long)(c0 + i) * R + r0 + tx] = tile[tx][i];
}

// ksum[c] = sum_b k[b][c]   (k = qkv cols [2048,4096), ld 6144)
__global__ __launch_bounds__(256) void ksum_kernel(const bf16_t* __restrict__ qkv,
                                                   float* __restrict__ ksum) {
  const int col = blockIdx.x * 256 + threadIdx.x;
  const int r0 = blockIdx.y * 256;
  const bf16_t* k = qkv + 2048;
  float s = 0.f;
  for (int r = 0; r < 256; ++r) s += (float)k[(long)(r0 + r) * 6144 + col];
  atomicAdd(&ksum[col], s);
}

// P[h][d][e] += sum_b k[b, h*128+d] * v[b, h*128+e]
__global__ __launch_bounds__(256) void kv_kernel(const bf16_t* __restrict__ qkv,
                                                 float* __restrict__ P) {
  const int h = blockIdx.x, sp = blockIdx.y;
  const int t = threadIdx.x;
  __shared__ __align__(16) bf16_t kS[64 * 128];
  __shared__ __align__(16) bf16_t vS[64 * 128];
  const int d0 = (t >> 4) * 8, e0 = (t & 15) * 8;
  const int srow = t >> 4, scol = (t & 15) * 8;
  float acc[8][8] = {};
  const bf16_t* kp = qkv + 2048 + h * 128;
  const bf16_t* vp = qkv + 4096 + h * 128;
  const long base = (long)sp * 512 * 6144;
  for (int c0 = 0; c0 < 512; c0 += 64) {
#pragma unroll
    for (int it = 0; it < 4; ++it) {
      load_lds16(kp + base + (long)(c0 + it * 16 + srow) * 6144 + scol, &kS[it * 2048 + t * 8]);
      load_lds16(vp + base + (long)(c0 + it * 16 + srow) * 6144 + scol, &vS[it * 2048 + t * 8]);
    }
    __syncthreads();
    for (int bb = 0; bb < 64; ++bb) {
      const bf16x8 kk = *(const bf16x8*)&kS[bb * 128 + d0];
      const bf16x8 vv = *(const bf16x8*)&vS[bb * 128 + e0];
      float kf[8], vf[8];
#pragma unroll
      for (int r = 0; r < 8; ++r) { kf[r] = (float)kk[r]; vf[r] = (float)vv[r]; }
#pragma unroll
      for (int a = 0; a < 8; ++a)
#pragma unroll
        for (int b2 = 0; b2 < 8; ++b2) acc[a][b2] += kf[a] * vf[b2];
    }
    __syncthreads();
  }
  float* Ph = P + (long)h * 16384;
#pragma unroll
  for (int a = 0; a < 8; ++a)
#pragma unroll
    for (int b2 = 0; b2 < 8; ++b2)
      atomicAdd(&Ph[(d0 + a) * 128 + e0 + b2], acc[a][b2]);
}

__global__ __launch_bounds__(256) void cvt_bf(const float* __restrict__ P,
                                              bf16_t* __restrict__ o, int n) {
  const int i = blockIdx.x * 256 + threadIdx.x;
  if (i < n) o[i] = (bf16_t)P[i];
}

// z[b][h] = 1 / (dot(q[b,h,:], ksum[h,:]) + 1e-6); then q *= z in-place
__global__ __launch_bounds__(256) void z_kernel(bf16_t* __restrict__ qkv,
                                                const float* __restrict__ ksum) {
  __shared__ float ks[2048];
  const int t = threadIdx.x;
  for (int i = t; i < 2048; i += 256) ks[i] = ksum[i];
  __syncthreads();
  const int b = blockIdx.x * 16 + (t >> 4);
  const int h = t & 15;
  bf16_t* qr = qkv + (long)b * 6144 + h * 128;
  bf16x8 qq[16];
  float s = 0.f;
#pragma unroll
  for (int i = 0; i < 16; ++i) {
    qq[i] = *(const bf16x8*)&qr[i * 8];
#pragma unroll
    for (int r = 0; r < 8; ++r) s += (float)qq[i][r] * ks[h * 128 + i * 8 + r];
  }
  const float z = 1.f / (s + 1e-6f);
#pragma unroll
  for (int i = 0; i < 16; ++i) {
#pragma unroll
    for (int r = 0; r < 8; ++r) qq[i][r] = (bf16_t)((float)qq[i][r] * z);
    *(bf16x8*)&qr[i * 8] = qq[i];
  }
}

extern "C" void kernel_launch(void* const* d_in, const int* in_sizes, int n_in,
                              void* d_out, int out_size, void* d_ws, size_t ws_size,
                              hipStream_t stream) {
  const float* x    = (const float*)d_in[0];
  const float* Wq   = (const float*)d_in[1];
  const float* Wk   = (const float*)d_in[2];
  const float* Wv   = (const float*)d_in[3];
  const float* Wo   = (const float*)d_in[4];
  const float* bo   = (const float*)d_in[5];
  const float* Wg   = (const float*)d_in[6];
  const float* bg   = (const float*)d_in[7];
  const float* Wout = (const float*)d_in[8];
  const float* bout = (const float*)d_in[9];

  char* ws = (char*)d_ws;
  size_t off = 0;
  auto alloc = [&](size_t bytes) -> void* {
    void* p = ws + off;
    off += (bytes + 255) & ~(size_t)255;
    return p;
  };
  bf16_t* concat = (bf16_t*)alloc((size_t)B_SZ * 4096 * 2);   // [op | x] bf16
  bf16_t* qkv    = (bf16_t*)alloc((size_t)B_SZ * 6144 * 2);   // [q | k | v]
  bf16_t* outb   = (bf16_t*)alloc((size_t)B_SZ * DIN * 2);
  bf16_t* WqkvT  = (bf16_t*)alloc((size_t)6144 * DIN * 2);
  bf16_t* WoT    = (bf16_t*)alloc((size_t)DIN * DV * 2);
  bf16_t* WgT    = (bf16_t*)alloc((size_t)DIN * 4096 * 2);
  bf16_t* WoutT  = (bf16_t*)alloc((size_t)DOUT * DIN * 2);
  float*  P      = (float*)alloc((size_t)NH * 128 * 128 * 4);
  bf16_t* kvbf   = (bf16_t*)alloc((size_t)NH * 128 * 128 * 2);
  bf16_t* G      = (bf16_t*)alloc((size_t)DIN * DK * 2);      // (blockdiag(kv) @ Wo)^T
  float*  ksum   = (float*)alloc((size_t)DK * 4);

  hipMemsetAsync(P, 0, (size_t)NH * 128 * 128 * 4, stream);
  hipMemsetAsync(ksum, 0, (size_t)DK * 4, stream);

  // single fused prep dispatch: cvt_x + all 6 weight transposes
  prep_kernel<<<32768 + 25600, 256, 0, stream>>>(x, Wq, Wk, Wv, Wo, Wg, Wout,
                                                 concat, WqkvT, WoT, WgT, WoutT);

  const bf16_t* xb = concat + 2048;  // bf16 x view, lda=4096

  // fused q|k|v projection: [B,2048] @ [2048,6144] -> qkv, relu-feat on q,k
  gemm256<1><<<dim3(24, 64, 1), 512, 0, stream>>>(xb, 4096, 0, WqkvT, 2048, 0,
                                                  qkv, 6144, 0, 2048, nullptr, nullptr);

  ksum_kernel<<<dim3(8, 64), 256, 0, stream>>>(qkv, ksum);
  kv_kernel<<<dim3(16, 32), 256, 0, stream>>>(qkv, P);
  cvt_bf<<<1024, 256, 0, stream>>>(P, kvbf, NH * 128 * 128);
  z_kernel<<<B_SZ / 16, 256, 0, stream>>>(qkv, ksum);  // also scales q by z

  // G[j][h*128+d] = sum_e kv_h[d][e] * WoT[j][h*128+e]  (per-head kv@Wo, transposed)
  gemm_bt<0><<<dim3(1, 16, 16), 256, 0, stream>>>(WoT, 2048, 128, kvbf, 128, 16384,
                                                  G, 2048, 128, 128, nullptr, nullptr);

  // out_proj = qz @ G^T + bo -> concat cols [0,2048)
  gemm256<2><<<dim3(8, 64, 1), 512, 0, stream>>>(qkv, 6144, 0, G, 2048, 0,
                                                 concat, 4096, 0, 2048, bo, nullptr);

  // gate GEMM over concat (K=4096), epilogue: sigmoid-mix -> outb
  gemm256<4><<<dim3(8, 64, 1), 512, 0, stream>>>(concat, 4096, 0, WgT, 4096, 0,
                                                 outb, 2048, 0, 4096, bg, x);

  // final: outb @ Wout + bout -> d_out (f32)
  gemm_bt<5><<<dim3(4, 128, 1), 256, 0, stream>>>(outb, 2048, 0, WoutT, 2048, 0,
                                                  d_out, 512, 0, 2048, bout, nullptr);
}

// Round 6
// 1490.676 us; speedup vs baseline: 1.0208x; 1.0208x over previous
//
#include <hip/hip_runtime.h>
#include <hip/hip_bf16.h>
#include <math.h>

typedef __bf16 bf16_t;
typedef __attribute__((ext_vector_type(8))) __bf16 bf16x8;
typedef __attribute__((ext_vector_type(4))) __bf16 bf16x4;
typedef __attribute__((ext_vector_type(16))) float f32x16;

#define DEVI __device__ __forceinline__

constexpr int B_SZ = 16384, DIN = 2048, DK = 2048, DV = 2048, NH = 16, DOUT = 512;

DEVI void load_lds16(const void* gptr, void* lptr) {
  __builtin_amdgcn_global_load_lds(
      (const __attribute__((address_space(1))) unsigned int*)gptr,
      (__attribute__((address_space(3))) unsigned int*)lptr,
      16, 0, 0);
}

// ---------------------------------------------------------------------------
// 256x256 bf16 GEMM (B transposed), BK=64, 512 thr = 8 waves (2M x 4N).
// Each wave owns 128x64 via acc[4][2] of 32x32x16 MFMA.
// LDS 128 KiB: 2 buffers x (A 256x64 | B 256x64), rows 128 B.
// Swizzle v2 (r3: conflicts -> 0): 16B-slot ^= f(row), f(r)=(r&7)^((r>>3)&3).
// global_load_lds writes linearly -> swizzle pre-applied on the GLOBAL source.
//
// r6 schedule: within-wave read/MFMA overlap via counted lgkmcnt.
// r5 showed zero LDS/MFMA overlap (per-tile ~4810 cyc = LDS 2040 + MFMA 2066
// serial): all waves re-sync at each barrier, so read bursts and MFMA bursts
// alternate chip-wide. Fix: issue ALL 24 ds_reads of the tile upfront
// (order pinned: [a0,bq] | a1 | a2 | a3 via sched_barrier separators), then
// gate each 8-MFMA quad on lgkmcnt(12/8/4/0). Reads for quads 1-3 execute in
// the LDS pipe concurrently with MFMA of earlier quads.
// Hazard ledger (unchanged from r4/r5):
//  - mid-tile barrier (after quad m1) precedes stageB(t+2): every wave
//    passed lgkmcnt(12), so all bq reads of buf[cur].B are retired.
//  - end-of-tile vmcnt(4)+barrier: retires (t+1).A (issued this tile) and
//    (t+1).B (issued last tile, older) => buf^1 fully staged before the next
//    tile's reads; (t+2).B's 4 loads stay in flight. Never vmcnt(0) in
//    steady state.
//  - stageA(t+1) writes buf^1.A: all waves' reads of buf^1 (tile t-1)
//    retired by their lgkmcnt(0) before the end-of-(t-1) barrier.
// ---------------------------------------------------------------------------
template <int EPI>
__global__ __launch_bounds__(512, 2) void gemm256(
    const bf16_t* __restrict__ A, int lda, long aZ,
    const bf16_t* __restrict__ Bt, int ldb, long bZ,
    void* __restrict__ Cv, int ldc, long cZ, int K,
    const float* __restrict__ aux1,   // bias
    const float* __restrict__ aux2) { // x (EPI4)
  __shared__ __align__(16) bf16_t lds[2][2][256 * 64];
  const int tid = threadIdx.x;
  // XCD-bijective swizzle (all launch grids have nwg % 8 == 0)
  const int gx = gridDim.x;
  const int nwg = gx * gridDim.y;
  int flat = blockIdx.y * gx + blockIdx.x;
  flat = (flat & 7) * (nwg >> 3) + (flat >> 3);
  const int bn = flat % gx, bm = flat / gx;
  const int bz = blockIdx.z;

  const int lane = tid & 63, w = tid >> 6;
  const int wr = w >> 2, wc = w & 3;      // wave 2x4 -> (128-row, 64-col) tile
  const int lm = lane & 31, lh = lane >> 5;

  const bf16_t* __restrict__ Ab = A + (long)bm * 256 * lda + (long)bz * aZ;
  const bf16_t* __restrict__ Bb = Bt + (long)bn * 256 * ldb + (long)bz * bZ;

  // staging: granule g = tid within an 8KB (64-row) chunk; pre-swizzled source.
  const int srow = tid >> 3;                       // 0..63
  const int fs = (srow & 7) ^ ((srow >> 3) & 3);
  const int sslot = (tid & 7) ^ fs;                // inverse swizzle on source
  const long aOff = (long)srow * lda + sslot * 8;
  const long bOff = (long)srow * ldb + sslot * 8;
  char* const ldsc = (char*)&lds[0][0][0];         // buf stride 65536, mat 32768

  // fragment read addressing (swizzled). All read-row bases are multiples of
  // 32, so f(row) = (lm&7) ^ ((lm>>3)&3) for every fragment read.
  const int xorv = (lm & 7) ^ ((lm >> 3) & 3);
  const int rbA = (wr * 128 + lm) * 128;           // row byte base, A
  const int rbB = (wc * 64 + lm) * 128 + 32768;    // row byte base, B
  int sl16[4];
#pragma unroll
  for (int s = 0; s < 4; ++s) sl16[s] = (((2 * s) | lh) ^ xorv) * 16;

  auto stageA = [&](int buf, int t, int h) {       // h: 128-row half; 2 loads
    const bf16_t* p = Ab + aOff + t * 64 + (long)h * 128 * lda;
    char* d = ldsc + buf * 65536 + h * 16384 + tid * 16;
    load_lds16(p, d);
    load_lds16(p + (long)64 * lda, d + 8192);
  };
  auto stageB = [&](int buf, int t, int h) {
    const bf16_t* p = Bb + bOff + t * 64 + (long)h * 128 * ldb;
    char* d = ldsc + buf * 65536 + 32768 + h * 16384 + tid * 16;
    load_lds16(p, d);
    load_lds16(p + (long)64 * ldb, d + 8192);
  };

  f32x16 acc[4][2] = {};
  const int NT = K >> 6;

  // prologue: tile0 full -> buf0; tile1 B -> buf1 (A of tile1 staged in iter0)
  stageA(0, 0, 0); stageA(0, 0, 1); stageB(0, 0, 0); stageB(0, 0, 1);
  if (NT > 1) {
    stageB(1, 1, 0); stageB(1, 1, 1);
    asm volatile("s_waitcnt vmcnt(4)" ::: "memory");  // tile0 landed, t1.B flying
  } else {
    asm volatile("s_waitcnt vmcnt(0)" ::: "memory");
  }
  __builtin_amdgcn_sched_barrier(0);
  __builtin_amdgcn_s_barrier();

  for (int t = 0; t < NT; ++t) {
    const int cur = t & 1;
    const char* base = ldsc + cur * 65536;
    bf16x8 a0[4], a1[4], a2[4], a3[4], bq[2][4];
    // ---- issue all 24 reads; FIFO order pinned: [a0,bq](12) | a1 | a2 | a3
#pragma unroll
    for (int s = 0; s < 4; ++s)
      a0[s] = *(const bf16x8*)(base + rbA + 0 * 4096 + sl16[s]);
#pragma unroll
    for (int j = 0; j < 2; ++j)
#pragma unroll
      for (int s = 0; s < 4; ++s)
        bq[j][s] = *(const bf16x8*)(base + rbB + j * 4096 + sl16[s]);
    __builtin_amdgcn_sched_barrier(0);
#pragma unroll
    for (int s = 0; s < 4; ++s)
      a1[s] = *(const bf16x8*)(base + rbA + 1 * 4096 + sl16[s]);
    __builtin_amdgcn_sched_barrier(0);
#pragma unroll
    for (int s = 0; s < 4; ++s)
      a2[s] = *(const bf16x8*)(base + rbA + 2 * 4096 + sl16[s]);
    __builtin_amdgcn_sched_barrier(0);
#pragma unroll
    for (int s = 0; s < 4; ++s)
      a3[s] = *(const bf16x8*)(base + rbA + 3 * 4096 + sl16[s]);
    __builtin_amdgcn_sched_barrier(0);
    if (t + 1 < NT) { stageA(cur ^ 1, t + 1, 0); stageA(cur ^ 1, t + 1, 1); }
    // ---- quad m0 (needs a0 + bq: oldest 12 reads) ----
    asm volatile("s_waitcnt lgkmcnt(12)" ::: "memory");
    __builtin_amdgcn_sched_barrier(0);
    __builtin_amdgcn_s_setprio(1);
#pragma unroll
    for (int s = 0; s < 4; ++s) {
      acc[0][0] = __builtin_amdgcn_mfma_f32_32x32x16_bf16(a0[s], bq[0][s], acc[0][0], 0, 0, 0);
      acc[0][1] = __builtin_amdgcn_mfma_f32_32x32x16_bf16(a0[s], bq[1][s], acc[0][1], 0, 0, 0);
    }
    __builtin_amdgcn_s_setprio(0);
    // ---- quad m1 (needs a1) ----
    asm volatile("s_waitcnt lgkmcnt(8)" ::: "memory");
    __builtin_amdgcn_sched_barrier(0);
    __builtin_amdgcn_s_setprio(1);
#pragma unroll
    for (int s = 0; s < 4; ++s) {
      acc[1][0] = __builtin_amdgcn_mfma_f32_32x32x16_bf16(a1[s], bq[0][s], acc[1][0], 0, 0, 0);
      acc[1][1] = __builtin_amdgcn_mfma_f32_32x32x16_bf16(a1[s], bq[1][s], acc[1][1], 0, 0, 0);
    }
    __builtin_amdgcn_s_setprio(0);
    __builtin_amdgcn_s_barrier();   // every wave passed lgkm(12) => bq retired
    if (t + 2 < NT) { stageB(cur, t + 2, 0); stageB(cur, t + 2, 1); }
    // ---- quad m2 (needs a2) ----
    asm volatile("s_waitcnt lgkmcnt(4)" ::: "memory");
    __builtin_amdgcn_sched_barrier(0);
    __builtin_amdgcn_s_setprio(1);
#pragma unroll
    for (int s = 0; s < 4; ++s) {
      acc[2][0] = __builtin_amdgcn_mfma_f32_32x32x16_bf16(a2[s], bq[0][s], acc[2][0], 0, 0, 0);
      acc[2][1] = __builtin_amdgcn_mfma_f32_32x32x16_bf16(a2[s], bq[1][s], acc[2][1], 0, 0, 0);
    }
    __builtin_amdgcn_s_setprio(0);
    // ---- quad m3 (needs a3) ----
    asm volatile("s_waitcnt lgkmcnt(0)" ::: "memory");
    __builtin_amdgcn_sched_barrier(0);
    __builtin_amdgcn_s_setprio(1);
#pragma unroll
    for (int s = 0; s < 4; ++s) {
      acc[3][0] = __builtin_amdgcn_mfma_f32_32x32x16_bf16(a3[s], bq[0][s], acc[3][0], 0, 0, 0);
      acc[3][1] = __builtin_amdgcn_mfma_f32_32x32x16_bf16(a3[s], bq[1][s], acc[3][1], 0, 0, 0);
    }
    __builtin_amdgcn_s_setprio(0);
    if (t + 2 < NT) asm volatile("s_waitcnt vmcnt(4)" ::: "memory");
    else            asm volatile("s_waitcnt vmcnt(0)" ::: "memory");
    __builtin_amdgcn_sched_barrier(0);
    __builtin_amdgcn_s_barrier();   // buf^1 fully staged for next tile
  }

  // C/D: col = lane&31, row = (reg&3) + 8*(reg>>2) + 4*(lane>>5)
#pragma unroll
  for (int i = 0; i < 4; ++i) {
#pragma unroll
    for (int j = 0; j < 2; ++j) {
      const int col = bn * 256 + wc * 64 + j * 32 + lm;
#pragma unroll
      for (int r = 0; r < 16; ++r) {
        const int row = bm * 256 + wr * 128 + i * 32 + (r & 3) + 8 * (r >> 2) + 4 * lh;
        const long cidx = (long)row * ldc + (long)bz * cZ + col;
        float val = acc[i][j][r];
        if (EPI == 0) {
          ((bf16_t*)Cv)[cidx] = (bf16_t)val;
        } else if (EPI == 1) {
          if (col < 4096) val = fmaxf(val, 0.f) + 1e-4f;  // q,k feat; v plain
          ((bf16_t*)Cv)[cidx] = (bf16_t)val;
        } else if (EPI == 2) {
          val += aux1[col];
          ((bf16_t*)Cv)[cidx] = (bf16_t)val;
        } else if (EPI == 4) {
          const float g = 1.f / (1.f + __expf(-(val + aux1[col])));
          const float op = (float)A[(long)row * lda + col];  // concat cols [0,2048)
          const float xx = aux2[(long)row * DIN + col];
          ((bf16_t*)Cv)[cidx] = (bf16_t)(g * op + (1.f - g) * xx);
        } else if (EPI == 5) {
          ((float*)Cv)[cidx] = val + aux1[col];
        }
      }
    }
  }
}

// ---------------------------------------------------------------------------
// legacy 128x128 GEMM — kept for the small/odd shapes (G per-head, final N=512)
// ---------------------------------------------------------------------------
template <int EPI>
__global__ __launch_bounds__(256, 4) void gemm_bt(
    const bf16_t* __restrict__ A, int lda, long aZ,
    const bf16_t* __restrict__ Bt, int ldb, long bZ,
    void* __restrict__ Cv, int ldc, long cZ, int K,
    const float* __restrict__ aux1,
    const float* __restrict__ aux2) {
  __shared__ __align__(16) bf16_t As[2][128 * 32];
  __shared__ __align__(16) bf16_t Bs[2][128 * 32];
  const int tid = threadIdx.x;
  const int bn = blockIdx.x, bm = blockIdx.y, bz = blockIdx.z;
  const int lane = tid & 63, w = tid >> 6;
  const int wm = (w & 1) * 64, wn = (w >> 1) * 64;
  const int lm = lane & 31, lh = lane >> 5;

  const bf16_t* __restrict__ Ab = A + (long)bm * 128 * lda + (long)bz * aZ;
  const bf16_t* __restrict__ Bb = Bt + (long)bn * 128 * ldb + (long)bz * bZ;

  const int srow = tid >> 2, scol = (tid & 3) * 8;
  const long aRow = (long)srow * lda + scol;
  const long bRow = (long)srow * ldb + scol;

  const char* aBase = (const char*)As + (wm + lm) * 64 + lh * 16;
  const char* bBase = (const char*)Bs + (wn + lm) * 64 + lh * 16;

  f32x16 acc[2][2] = {};

  for (int k0 = 0; k0 < K; k0 += 64) {
    const bf16_t* ap = Ab + aRow + k0;
    const bf16_t* bp = Bb + bRow + k0;
    load_lds16(ap, &As[0][tid * 8]);
    load_lds16(ap + (long)64 * lda, &As[0][2048 + tid * 8]);
    load_lds16(ap + 32, &As[1][tid * 8]);
    load_lds16(ap + (long)64 * lda + 32, &As[1][2048 + tid * 8]);
    load_lds16(bp, &Bs[0][tid * 8]);
    load_lds16(bp + (long)64 * ldb, &Bs[0][2048 + tid * 8]);
    load_lds16(bp + 32, &Bs[1][tid * 8]);
    load_lds16(bp + (long)64 * ldb + 32, &Bs[1][2048 + tid * 8]);
    __syncthreads();
#pragma unroll
    for (int s = 0; s < 4; ++s) {
      const int off = (s >> 1) * 8192 + (s & 1) * 32;
      const bf16x8 af0 = *(const bf16x8*)(aBase + off);
      const bf16x8 af1 = *(const bf16x8*)(aBase + off + 2048);
      const bf16x8 bf0 = *(const bf16x8*)(bBase + off);
      const bf16x8 bf1 = *(const bf16x8*)(bBase + off + 2048);
      acc[0][0] = __builtin_amdgcn_mfma_f32_32x32x16_bf16(af0, bf0, acc[0][0], 0, 0, 0);
      acc[0][1] = __builtin_amdgcn_mfma_f32_32x32x16_bf16(af0, bf1, acc[0][1], 0, 0, 0);
      acc[1][0] = __builtin_amdgcn_mfma_f32_32x32x16_bf16(af1, bf0, acc[1][0], 0, 0, 0);
      acc[1][1] = __builtin_amdgcn_mfma_f32_32x32x16_bf16(af1, bf1, acc[1][1], 0, 0, 0);
    }
    __syncthreads();
  }

#pragma unroll
  for (int i = 0; i < 2; ++i) {
#pragma unroll
    for (int j = 0; j < 2; ++j) {
      const int col = bn * 128 + wn + j * 32 + lm;
#pragma unroll
      for (int r = 0; r < 16; ++r) {
        const int row = bm * 128 + wm + i * 32 + (r & 3) + 8 * (r >> 2) + 4 * lh;
        const long cidx = (long)row * ldc + (long)bz * cZ + col;
        float val = acc[i][j][r];
        if (EPI == 0) {
          ((bf16_t*)Cv)[cidx] = (bf16_t)val;
        } else if (EPI == 5) {
          ((float*)Cv)[cidx] = val + aux1[col];
        }
      }
    }
  }
}

// ---------------------------------------------------------------------------
// Fused prep: cvt_x (blocks [0, 32768)) + 6 weight transposes (f32 -> bf16^T)
// ---------------------------------------------------------------------------
__global__ __launch_bounds__(256) void prep_kernel(
    const float* __restrict__ x, const float* __restrict__ Wq,
    const float* __restrict__ Wk, const float* __restrict__ Wv,
    const float* __restrict__ Wo, const float* __restrict__ Wg,
    const float* __restrict__ Wout, bf16_t* __restrict__ concat,
    bf16_t* __restrict__ WqkvT, bf16_t* __restrict__ WoT,
    bf16_t* __restrict__ WgT, bf16_t* __restrict__ WoutT) {
  const int tid = threadIdx.x;
  int b = blockIdx.x;
  if (b < 32768) {  // cvt_x: x f32 -> bf16 into concat cols [2048,4096)
    const long i = ((long)b * 256 + tid) * 4;
    const long row = i >> 11;
    const int col = (int)(i & 2047);
    const float4 f = *(const float4*)&x[i];
    bf16x4 o;
    o[0] = (bf16_t)f.x; o[1] = (bf16_t)f.y; o[2] = (bf16_t)f.z; o[3] = (bf16_t)f.w;
    *(bf16x4*)&concat[row * 4096 + 2048 + col] = o;
    return;
  }
  b -= 32768;
  const float* in; bf16_t* out; int R, C;
  if (b < 4096)       { in = Wq;   out = WqkvT;                     R = 2048; C = 2048; }
  else if (b < 8192)  { in = Wk;   out = WqkvT + (size_t)2048*2048; R = 2048; C = 2048; b -= 4096; }
  else if (b < 12288) { in = Wv;   out = WqkvT + (size_t)4096*2048; R = 2048; C = 2048; b -= 8192; }
  else if (b < 16384) { in = Wo;   out = WoT;                       R = 2048; C = 2048; b -= 12288; }
  else if (b < 24576) { in = Wg;   out = WgT;                       R = 4096; C = 2048; b -= 16384; }
  else                { in = Wout; out = WoutT;                     R = 2048; C = 512;  b -= 24576; }
  const int CB = C / 32;
  const int c0 = (b % CB) * 32, r0 = (b / CB) * 32;
  __shared__ bf16_t tile[32][33];
  const int tx = tid & 31, ty = tid >> 5;
  for (int i = ty; i < 32; i += 8)
    tile[i][tx] = (bf16_t)in[(long)(r0 + i) * C + c0 + tx];
  __syncthreads();
  for (int i = ty; i < 32; i += 8)
    out[(long)(c0 + i) * R + r0 + tx] = tile[tx][i];
}

// ksum[c] = sum_b k[b][c]   (k = qkv cols [2048,4096), ld 6144)
__global__ __launch_bounds__(256) void ksum_kernel(const bf16_t* __restrict__ qkv,
                                                   float* __restrict__ ksum) {
  const int col = blockIdx.x * 256 + threadIdx.x;
  const int r0 = blockIdx.y * 256;
  const bf16_t* k = qkv + 2048;
  float s = 0.f;
  for (int r = 0; r < 256; ++r) s += (float)k[(long)(r0 + r) * 6144 + col];
  atomicAdd(&ksum[col], s);
}

// P[h][d][e] += sum_b k[b, h*128+d] * v[b, h*128+e]
__global__ __launch_bounds__(256) void kv_kernel(const bf16_t* __restrict__ qkv,
                                                 float* __restrict__ P) {
  const int h = blockIdx.x, sp = blockIdx.y;
  const int t = threadIdx.x;
  __shared__ __align__(16) bf16_t kS[64 * 128];
  __shared__ __align__(16) bf16_t vS[64 * 128];
  const int d0 = (t >> 4) * 8, e0 = (t & 15) * 8;
  const int srow = t >> 4, scol = (t & 15) * 8;
  float acc[8][8] = {};
  const bf16_t* kp = qkv + 2048 + h * 128;
  const bf16_t* vp = qkv + 4096 + h * 128;
  const long base = (long)sp * 512 * 6144;
  for (int c0 = 0; c0 < 512; c0 += 64) {
#pragma unroll
    for (int it = 0; it < 4; ++it) {
      load_lds16(kp + base + (long)(c0 + it * 16 + srow) * 6144 + scol, &kS[it * 2048 + t * 8]);
      load_lds16(vp + base + (long)(c0 + it * 16 + srow) * 6144 + scol, &vS[it * 2048 + t * 8]);
    }
    __syncthreads();
    for (int bb = 0; bb < 64; ++bb) {
      const bf16x8 kk = *(const bf16x8*)&kS[bb * 128 + d0];
      const bf16x8 vv = *(const bf16x8*)&vS[bb * 128 + e0];
      float kf[8], vf[8];
#pragma unroll
      for (int r = 0; r < 8; ++r) { kf[r] = (float)kk[r]; vf[r] = (float)vv[r]; }
#pragma unroll
      for (int a = 0; a < 8; ++a)
#pragma unroll
        for (int b2 = 0; b2 < 8; ++b2) acc[a][b2] += kf[a] * vf[b2];
    }
    __syncthreads();
  }
  float* Ph = P + (long)h * 16384;
#pragma unroll
  for (int a = 0; a < 8; ++a)
#pragma unroll
    for (int b2 = 0; b2 < 8; ++b2)
      atomicAdd(&Ph[(d0 + a) * 128 + e0 + b2], acc[a][b2]);
}

__global__ __launch_bounds__(256) void cvt_bf(const float* __restrict__ P,
                                              bf16_t* __restrict__ o, int n) {
  const int i = blockIdx.x * 256 + threadIdx.x;
  if (i < n) o[i] = (bf16_t)P[i];
}

// z[b][h] = 1 / (dot(q[b,h,:], ksum[h,:]) + 1e-6); then q *= z in-place
__global__ __launch_bounds__(256) void z_kernel(bf16_t* __restrict__ qkv,
                                                const float* __restrict__ ksum) {
  __shared__ float ks[2048];
  const int t = threadIdx.x;
  for (int i = t; i < 2048; i += 256) ks[i] = ksum[i];
  __syncthreads();
  const int b = blockIdx.x * 16 + (t >> 4);
  const int h = t & 15;
  bf16_t* qr = qkv + (long)b * 6144 + h * 128;
  bf16x8 qq[16];
  float s = 0.f;
#pragma unroll
  for (int i = 0; i < 16; ++i) {
    qq[i] = *(const bf16x8*)&qr[i * 8];
#pragma unroll
    for (int r = 0; r < 8; ++r) s += (float)qq[i][r] * ks[h * 128 + i * 8 + r];
  }
  const float z = 1.f / (s + 1e-6f);
#pragma unroll
  for (int i = 0; i < 16; ++i) {
#pragma unroll
    for (int r = 0; r < 8; ++r) qq[i][r] = (bf16_t)((float)qq[i][r] * z);
    *(bf16x8*)&qr[i * 8] = qq[i];
  }
}

extern "C" void kernel_launch(void* const* d_in, const int* in_sizes, int n_in,
                              void* d_out, int out_size, void* d_ws, size_t ws_size,
                              hipStream_t stream) {
  const float* x    = (const float*)d_in[0];
  const float* Wq   = (const float*)d_in[1];
  const float* Wk   = (const float*)d_in[2];
  const float* Wv   = (const float*)d_in[3];
  const float* Wo   = (const float*)d_in[4];
  const float* bo   = (const float*)d_in[5];
  const float* Wg   = (const float*)d_in[6];
  const float* bg   = (const float*)d_in[7];
  const float* Wout = (const float*)d_in[8];
  const float* bout = (const float*)d_in[9];

  char* ws = (char*)d_ws;
  size_t off = 0;
  auto alloc = [&](size_t bytes) -> void* {
    void* p = ws + off;
    off += (bytes + 255) & ~(size_t)255;
    return p;
  };
  bf16_t* concat = (bf16_t*)alloc((size_t)B_SZ * 4096 * 2);   // [op | x] bf16
  bf16_t* qkv    = (bf16_t*)alloc((size_t)B_SZ * 6144 * 2);   // [q | k | v]
  bf16_t* outb   = (bf16_t*)alloc((size_t)B_SZ * DIN * 2);
  bf16_t* WqkvT  = (bf16_t*)alloc((size_t)6144 * DIN * 2);
  bf16_t* WoT    = (bf16_t*)alloc((size_t)DIN * DV * 2);
  bf16_t* WgT    = (bf16_t*)alloc((size_t)DIN * 4096 * 2);
  bf16_t* WoutT  = (bf16_t*)alloc((size_t)DOUT * DIN * 2);
  float*  P      = (float*)alloc((size_t)NH * 128 * 128 * 4);
  bf16_t* kvbf   = (bf16_t*)alloc((size_t)NH * 128 * 128 * 2);
  bf16_t* G      = (bf16_t*)alloc((size_t)DIN * DK * 2);      // (blockdiag(kv) @ Wo)^T
  float*  ksum   = (float*)alloc((size_t)DK * 4);

  hipMemsetAsync(P, 0, (size_t)NH * 128 * 128 * 4, stream);
  hipMemsetAsync(ksum, 0, (size_t)DK * 4, stream);

  // single fused prep dispatch: cvt_x + all 6 weight transposes
  prep_kernel<<<32768 + 25600, 256, 0, stream>>>(x, Wq, Wk, Wv, Wo, Wg, Wout,
                                                 concat, WqkvT, WoT, WgT, WoutT);

  const bf16_t* xb = concat + 2048;  // bf16 x view, lda=4096

  // fused q|k|v projection: [B,2048] @ [2048,6144] -> qkv, relu-feat on q,k
  gemm256<1><<<dim3(24, 64, 1), 512, 0, stream>>>(xb, 4096, 0, WqkvT, 2048, 0,
                                                  qkv, 6144, 0, 2048, nullptr, nullptr);

  ksum_kernel<<<dim3(8, 64), 256, 0, stream>>>(qkv, ksum);
  kv_kernel<<<dim3(16, 32), 256, 0, stream>>>(qkv, P);
  cvt_bf<<<1024, 256, 0, stream>>>(P, kvbf, NH * 128 * 128);
  z_kernel<<<B_SZ / 16, 256, 0, stream>>>(qkv, ksum);  // also scales q by z

  // G[j][h*128+d] = sum_e kv_h[d][e] * WoT[j][h*128+e]  (per-head kv@Wo, transposed)
  gemm_bt<0><<<dim3(1, 16, 16), 256, 0, stream>>>(WoT, 2048, 128, kvbf, 128, 16384,
                                                  G, 2048, 128, 128, nullptr, nullptr);

  // out_proj = qz @ G^T + bo -> concat cols [0,2048)
  gemm256<2><<<dim3(8, 64, 1), 512, 0, stream>>>(qkv, 6144, 0, G, 2048, 0,
                                                 concat, 4096, 0, 2048, bo, nullptr);

  // gate GEMM over concat (K=4096), epilogue: sigmoid-mix -> outb
  gemm256<4><<<dim3(8, 64, 1), 512, 0, stream>>>(concat, 4096, 0, WgT, 4096, 0,
                                                 outb, 2048, 0, 4096, bg, x);

  // final: outb @ Wout + bout -> d_out (f32)
  gemm_bt<5><<<dim3(4, 128, 1), 256, 0, stream>>>(outb, 2048, 0, WoutT, 2048, 0,
                                                  d_out, 512, 0, 2048, bout, nullptr);
}